// Round 15
// baseline (172.215 us; speedup 1.0000x reference)
//
#include <hip/hip_runtime.h>

// VectorAttention: B=4, C=32, H=256, W=256, HID=64, all fp32 in/out.
// hid_n = (Wq1@x + b1) - (Wk1@x)|neighbor ; scores = W2@relu(LN(hid)) via MFMA.
// fp16 intermediates. kh/v/Sk zero-padded (258x258).
// attn: 512-thread blocks, 2-way neighbor split; per-iteration kh+Sk register
// prefetch; pre-LN hid stored packed to LDS (RMW normalize); fp16 packed
// softmax accumulators (wv2/ssum2).

#define HWm 65536
#define NPIX 262144
#define PW 258
#define PHW 66564   // 258*258
#define LOG2E 1.44269504088896340736f

typedef __attribute__((ext_vector_type(8))) _Float16 half8;
typedef __attribute__((ext_vector_type(2))) _Float16 half2v;
typedef __attribute__((ext_vector_type(4))) float f32x4;

__device__ __forceinline__ unsigned pkh(float a, float b) {
    auto h = __builtin_amdgcn_cvt_pkrtz(a, b);   // __fp16 ext_vector(2)
    return __builtin_bit_cast(unsigned, h);
}
__device__ __forceinline__ half2v h2(unsigned u) { return __builtin_bit_cast(half2v, u); }
__device__ __forceinline__ unsigned u2(half2v h) { return __builtin_bit_cast(unsigned, h); }

// ---------------- kernel 0: weight prep ----------------
// Wall rows: 0-63 Wk1 | 64-127 Wq1 | 128-159 Wqkv[64:96] (v) | 160-191 Wg+I
__global__ __launch_bounds__(256) void prep_kernel(
    const float* __restrict__ Wqkv, const float* __restrict__ W1,
    const float* __restrict__ W2, const float* __restrict__ b1v,
    const float* __restrict__ Wg, const float* __restrict__ bgv,
    const float* __restrict__ lnw, const float* __restrict__ lnb,
    const float* __restrict__ b2, float* __restrict__ Wk1,
    float* __restrict__ Wq1, unsigned* __restrict__ W2A,
    unsigned* __restrict__ waA, float* __restrict__ biasF,
    unsigned* __restrict__ beta2G, float* __restrict__ b2adj)
{
    const int tid = threadIdx.x;
    for (int i = tid; i < 2048; i += 256) {
        const int d = i >> 5, c = i & 31;
        float aq = 0.f, ak = 0.f;
#pragma unroll
        for (int k = 0; k < 32; ++k) {
            const float w1 = W1[d * 32 + k];
            aq = fmaf(w1, Wqkv[k * 32 + c], aq);
            ak = fmaf(w1, Wqkv[(32 + k) * 32 + c], ak);
        }
        Wq1[i] = aq;
        Wk1[i] = ak;
    }
    // W2 A-fragments: fold lnw (assumed >0; ~0 -> dead channel) and log2e.
    for (int i = tid; i < 1024; i += 256) {
        const int w = i & 3;
        const int lane = (i >> 2) & 63;
        const int kb = (i >> 8) & 1;
        const int ct = (i >> 9) & 1;
        const int row = (lane & 15) + 16 * ct;
        const int k0 = kb * 32 + ((lane >> 4) & 3) * 8 + 2 * w;
        const float s0 = (fabsf(lnw[k0]) < 1e-8f) ? 0.f : lnw[k0] * LOG2E;
        const float s1 = (fabsf(lnw[k0 + 1]) < 1e-8f) ? 0.f : lnw[k0 + 1] * LOG2E;
        W2A[i] = pkh(W2[row * 64 + k0] * s0, W2[row * 64 + k0 + 1] * s1);
    }
    // beta pairs + adjusted b2 (handles lnw~0 channels exactly)
    for (int i = tid; i < 32; i += 256) {
        const float w0 = lnw[2 * i], w1 = lnw[2 * i + 1];
        const float be0 = (fabsf(w0) < 1e-8f) ? 0.f : lnb[2 * i] / w0;
        const float be1 = (fabsf(w1) < 1e-8f) ? 0.f : lnb[2 * i + 1] / w1;
        beta2G[i] = pkh(be0, be1);
    }
    for (int i = tid; i < 32; i += 256) {
        float acc = b2[i] * LOG2E;
        for (int d = 0; d < 64; ++d)
            if (fabsf(lnw[d]) < 1e-8f)
                acc += W2[i * 64 + d] * fmaxf(lnb[d], 0.f) * LOG2E;
        b2adj[i] = acc;
    }
    __syncthreads();
    // Wall A-fragments (fp16)
    for (int i = tid; i < 3072; i += 256) {
        const int t = i >> 8;
        const int l = (i >> 2) & 63;
        const int w2 = i & 3;
        const int row = 16 * t + (l & 15);
        const int k0 = ((l >> 4) & 3) * 8 + 2 * w2;
        float a0, a1;
        if (row < 64)        { a0 = Wk1[row * 32 + k0];            a1 = Wk1[row * 32 + k0 + 1]; }
        else if (row < 128)  { a0 = Wq1[(row - 64) * 32 + k0];     a1 = Wq1[(row - 64) * 32 + k0 + 1]; }
        else if (row < 160)  { a0 = Wqkv[(row - 64) * 32 + k0];    a1 = Wqkv[(row - 64) * 32 + k0 + 1]; }
        else {
            const int gr = row - 160;
            a0 = Wg[gr * 32 + k0]     + ((gr == k0)     ? 1.f : 0.f);
            a1 = Wg[gr * 32 + k0 + 1] + ((gr == k0 + 1) ? 1.f : 0.f);
        }
        waA[i] = pkh(a0, a1);
    }
    // bias fragments
    for (int i = tid; i < 3072; i += 256) {
        const int t = i >> 8;
        const int l = (i >> 2) & 63;
        const int r = i & 3;
        const int row = 16 * t + ((l >> 4) & 3) * 4 + r;
        float bv = 0.f;
        if (row >= 64 && row < 128) bv = b1v[row - 64];
        else if (row >= 160)        bv = bgv[row - 160];
        biasF[i] = bv;
    }
}

// ---------------- kernel 1: MFMA projections (fp16) ----------------
__global__ __launch_bounds__(256) void kv_kernel(
    const float* __restrict__ x, const half8* __restrict__ waA,
    const float4* __restrict__ biasF, unsigned* __restrict__ khP,
    unsigned* __restrict__ qhg, unsigned* __restrict__ vP,
    float* __restrict__ SkP, float* __restrict__ SqG,
    float* __restrict__ out)
{
    const int bid = blockIdx.x;
    const int tid = threadIdx.x;

    if (bid >= 1024) {
        const int t = (bid - 1024) * 256 + tid;
        if (t < 4112) {
            const int bb = t / 1028;
            const int rr = t - bb * 1028;
            int hh, ww;
            if (rr < 258)      { hh = 0;             ww = rr; }
            else if (rr < 516) { hh = 257;           ww = rr - 258; }
            else if (rr < 772) { hh = rr - 516 + 1;  ww = 0; }
            else               { hh = rr - 772 + 1;  ww = 257; }
            const size_t pixP = (size_t)bb * PHW + hh * PW + ww;
            uint4* kp = (uint4*)khP + pixP * 8;
            uint4* vp = (uint4*)vP + pixP * 4;
            const uint4 z = { 0u, 0u, 0u, 0u };
#pragma unroll
            for (int i = 0; i < 8; ++i) kp[i] = z;
#pragma unroll
            for (int i = 0; i < 4; ++i) vp[i] = z;
            SkP[pixP] = 0.f;
        }
        return;
    }

    __shared__ __align__(16) unsigned xT[256 * 16];   // 16 KB

    const int b = bid >> 8;
    const int h = bid & 255;
    const int pix0 = bid * 256;
    const int rowP0 = b * PHW + (h + 1) * PW + 1;

    {
        const float* xp = x + (size_t)b * (32 * HWm) + h * 256 + tid;
        float xv[32];
#pragma unroll
        for (int c = 0; c < 32; ++c) xv[c] = xp[c * HWm];
        unsigned* myx = &xT[tid * 16];
#pragma unroll
        for (int cc = 0; cc < 4; ++cc) {
            uint4 u;
            u.x = pkh(xv[cc * 8 + 0], xv[cc * 8 + 1]);
            u.y = pkh(xv[cc * 8 + 2], xv[cc * 8 + 3]);
            u.z = pkh(xv[cc * 8 + 4], xv[cc * 8 + 5]);
            u.w = pkh(xv[cc * 8 + 6], xv[cc * 8 + 7]);
            *(uint4*)(myx + (((cc + tid) & 3) * 4)) = u;
        }
    }
    // no barrier: wave-local staging + reads

    const int l = tid & 63;
    const int wid = tid >> 6;
    const int g = l >> 4;
    const int c15 = l & 15;

    half8 A[12];
    f32x4 bF[12];
#pragma unroll
    for (int t = 0; t < 12; ++t) {
        A[t] = waA[t * 64 + l];
        const float4 bv = biasF[t * 64 + l];
        bF[t][0] = bv.x; bF[t][1] = bv.y; bF[t][2] = bv.z; bF[t][3] = bv.w;
    }

#pragma unroll
    for (int pp = 0; pp < 4; ++pp) {
        const int pg = wid * 4 + pp;
        const int px = pg * 16 + c15;
        const half8 bfrag = *(const half8*)&xT[px * 16 + (((g + px) & 3) * 4)];

        f32x4 Ct[12];
#pragma unroll
        for (int t = 0; t < 12; ++t)
            Ct[t] = __builtin_amdgcn_mfma_f32_16x16x32_f16(A[t], bfrag, bF[t], 0, 0, 0);

        const size_t pixP = (size_t)(rowP0 + px);
        const int pixg = pix0 + px;

        float sk = 0.f;
        {
            char* krec = (char*)khP + pixP * 128 + g * 8;
#pragma unroll
            for (int t = 0; t < 4; ++t) {
                uint2 uu;
                uu.x = pkh(Ct[t][0], Ct[t][1]);
                uu.y = pkh(Ct[t][2], Ct[t][3]);
                *(uint2*)(krec + t * 32) = uu;
                sk += (Ct[t][0] + Ct[t][1]) + (Ct[t][2] + Ct[t][3]);
            }
        }
        float sq = 0.f;
        {
            char* qrec = (char*)qhg + (size_t)pixg * 128 + g * 8;
#pragma unroll
            for (int t = 4; t < 8; ++t) {
                uint2 uu;
                uu.x = pkh(Ct[t][0], Ct[t][1]);
                uu.y = pkh(Ct[t][2], Ct[t][3]);
                *(uint2*)(qrec + (t - 4) * 32) = uu;
                sq += (Ct[t][0] + Ct[t][1]) + (Ct[t][2] + Ct[t][3]);
            }
        }
        {
            char* vrec = (char*)vP + pixP * 64 + g * 8;
#pragma unroll
            for (int t = 8; t < 10; ++t) {
                uint2 uu;
                uu.x = pkh(Ct[t][0], Ct[t][1]);
                uu.y = pkh(Ct[t][2], Ct[t][3]);
                *(uint2*)(vrec + (t - 8) * 32) = uu;
            }
        }
        {
            float* op = out + (size_t)b * (32 * HWm) + h * 256 + px;
#pragma unroll
            for (int t = 10; t < 12; ++t) {
#pragma unroll
                for (int r = 0; r < 4; ++r)
                    op[(16 * (t - 10) + g * 4 + r) * HWm] = Ct[t][r];
            }
        }
        sk += __shfl_xor(sk, 16);
        sk += __shfl_xor(sk, 32);
        sq += __shfl_xor(sq, 16);
        sq += __shfl_xor(sq, 32);
        if (g == 0) {
            SkP[pixP] = sk;
            SqG[pixg] = sq;
        }
    }
}

// ---------------- kernel 2: MFMA attention: prefetch + LDS-RMW + fp16 acc ----------------
__global__ __launch_bounds__(512) void attn_kernel(
    const unsigned* __restrict__ qhg, const unsigned* __restrict__ khP,
    const unsigned* __restrict__ vP, const half8* __restrict__ w2a,
    const float* __restrict__ SkP, const float* __restrict__ SqG,
    const unsigned* __restrict__ beta2G, const float* __restrict__ b2adj,
    float* __restrict__ out)
{
    __shared__ __align__(16) char hidL[65536];   // 2 x 32KB hid; reused for merge

    const int tid = threadIdx.x;
    const int grp = tid >> 8;
    const int p = tid & 255;

    const int bid = blockIdx.x;
    const int swz = (bid & 7) * 128 + (bid >> 3);
    const int b = swz >> 8;
    const int trem = swz & 255;
    const int h0 = (trem >> 4) << 4;
    const int w0 = (trem & 15) << 4;

    const int l = tid & 63;
    const int lane15 = p & 15;
    const int q = (p >> 4) & 3;
    const int wrow = (p >> 6) & 3;

    const int row = p >> 4;
    const int h = h0 + row, w = w0 + lane15;
    const int pix = (b << 16) + (h << 8) + w;
    const int pixP = b * PHW + (h + 1) * PW + (w + 1);
    const int tileP = b * PHW + (h0 + 1) * PW + (w0 + 1);
    const int vbase0 = tileP + lane15;   // + g*PW + relOff per use

    // own-pixel qh, packed fp16 (persistent)
    unsigned qw[32];
    {
        const uint4* qp = (const uint4*)qhg + (size_t)pix * 8;
#pragma unroll
        for (int i = 0; i < 8; ++i) {
            const uint4 u = qp[i];
            qw[4 * i] = u.x; qw[4 * i + 1] = u.y; qw[4 * i + 2] = u.z; qw[4 * i + 3] = u.w;
        }
    }
    const float Sq = SqG[pix];

    const half8 a00 = w2a[0 * 64 + l];
    const half8 a01 = w2a[1 * 64 + l];
    const half8 a10 = w2a[2 * 64 + l];
    const half8 a11 = w2a[3 * 64 + l];

    float b2v[8];
    {
        const float4 t0 = *(const float4*)(b2adj + q * 4);
        const float4 t1 = *(const float4*)(b2adj + 16 + q * 4);
        b2v[0] = t0.x; b2v[1] = t0.y; b2v[2] = t0.z; b2v[3] = t0.w;
        b2v[4] = t1.x; b2v[5] = t1.y; b2v[6] = t1.z; b2v[7] = t1.w;
    }

    // fp16 packed accumulators: [gg*4 + {0,1}] = acc0 ch pairs, {2,3} = acc1
    half2v wv2[16], ssum2[16];
    const half2v zero2 = { (_Float16)0.f, (_Float16)0.f };
#pragma unroll
    for (int i = 0; i < 16; ++i) { wv2[i] = zero2; ssum2[i] = zero2; }

    const uint4* khP4 = (const uint4*)khP;
    char* const grpbase = hidL + (grp << 15);
    char* const myhid = grpbase + p * 128;
    const int myswz = (p & 7) << 4;

    const int cnt = grp ? 5 : 4;
    int relOff = grp ? 0 : (-PW - 1);
    int m3 = grp ? 1 : 0;            // n % 3 of current neighbor
    int nofs = pixP + relOff;

    // preload first neighbor's kh + Sk
    uint4 kc[8];
    {
        const uint4* kp0 = khP4 + (size_t)nofs * 8;
#pragma unroll
        for (int j = 0; j < 8; ++j) kc[j] = kp0[j];
    }
    float Sk = SkP[nofs];

#pragma unroll
    for (int nn = 0; nn < 5; ++nn) {
        if (nn >= cnt) break;

        // ---- prefetch next neighbor's kh + Sk (overlaps this iteration) ----
        const int step = (m3 == 2) ? (PW - 2) : 1;
        const int nofsN = nofs + step;
        uint4 kn[8];
        float SkN = 0.f;
        if (nn + 1 < cnt) {
            const uint4* kp = khP4 + (size_t)nofsN * 8;
#pragma unroll
            for (int j = 0; j < 8; ++j) kn[j] = kp[j];
            SkN = SkP[nofsN];
        }

        // ---- pass 1: pre-LN hid (already fp16-packed) -> LDS; stats ----
        float ss0 = 0.f, ss1 = 0.f;
#pragma unroll
        for (int cj = 0; cj < 8; ++cj) {
            const uint4 kcv = kc[cj];
            const half2v d0 = h2(qw[cj * 4 + 0]) - h2(kcv.x);
            const half2v d1 = h2(qw[cj * 4 + 1]) - h2(kcv.y);
            const half2v d2 = h2(qw[cj * 4 + 2]) - h2(kcv.z);
            const half2v d3 = h2(qw[cj * 4 + 3]) - h2(kcv.w);
            ss0 = __builtin_amdgcn_fdot2(d0, d0, ss0, false);
            ss1 = __builtin_amdgcn_fdot2(d1, d1, ss1, false);
            ss0 = __builtin_amdgcn_fdot2(d2, d2, ss0, false);
            ss1 = __builtin_amdgcn_fdot2(d3, d3, ss1, false);
            uint4 o;
            o.x = u2(d0); o.y = u2(d1); o.z = u2(d2); o.w = u2(d3);
            *(uint4*)(myhid + ((cj * 16) ^ myswz)) = o;
        }
        const float sum = Sq - Sk;
        const float sumsq = ss0 + ss1;
        const float mean = sum * 0.015625f;
        float var = fmaf(-mean, mean, sumsq * 0.015625f);
        var = fmaxf(var, 0.f);
        const float inv = __builtin_amdgcn_rcpf(sqrtf(var) + 1e-5f);
        const float nmi = -mean * inv;
        const half2v inv2 = { (_Float16)inv, (_Float16)inv };
        const half2v nmi2 = { (_Float16)nmi, (_Float16)nmi };

        // ---- pass 2: RMW normalize+relu in LDS ----
#pragma unroll
        for (int cj = 0; cj < 8; ++cj) {
            char* pp = myhid + ((cj * 16) ^ myswz);
            const uint4 t = *(const uint4*)pp;
            uint4 o;
#pragma unroll
            for (int j = 0; j < 4; ++j) {
                const unsigned tw = (j == 0) ? t.x : (j == 1) ? t.y : (j == 2) ? t.z : t.w;
                half2v nb = h2(beta2G[cj * 4 + j]) + nmi2;
                half2v u = __builtin_elementwise_fma(h2(tw), inv2, nb);
                u = __builtin_elementwise_max(u, zero2);
                const unsigned uo = u2(u);
                if (j == 0) o.x = uo; else if (j == 1) o.y = uo; else if (j == 2) o.z = uo; else o.w = uo;
            }
            *(uint4*)pp = o;
        }

        // ---- MFMA + packed softmax accumulate (wave-local rows) ----
#pragma unroll
        for (int gg = 0; gg < 4; ++gg) {
            const int g = wrow * 4 + gg;
            const int px = g * 16 + lane15;
            const char* bp = grpbase + px * 128;
            const int sw = (lane15 & 7) << 4;
            const half8 b0 = *(const half8*)(bp + ((q * 16) ^ sw));
            const half8 b1 = *(const half8*)(bp + (((4 + q) * 16) ^ sw));
            f32x4 acc0 = { b2v[0], b2v[1], b2v[2], b2v[3] };
            f32x4 acc1 = { b2v[4], b2v[5], b2v[6], b2v[7] };
            acc0 = __builtin_amdgcn_mfma_f32_16x16x32_f16(a00, b0, acc0, 0, 0, 0);
            acc0 = __builtin_amdgcn_mfma_f32_16x16x32_f16(a01, b1, acc0, 0, 0, 0);
            acc1 = __builtin_amdgcn_mfma_f32_16x16x32_f16(a10, b0, acc1, 0, 0, 0);
            acc1 = __builtin_amdgcn_mfma_f32_16x16x32_f16(a11, b1, acc1, 0, 0, 0);

            const int npP = vbase0 + g * PW + relOff;
            const unsigned* vp = vP + (size_t)npP * 16;
            const uint2 vA = *(const uint2*)(vp + q * 2);
            const uint2 vB = *(const uint2*)(vp + 8 + q * 2);

            const half2v e01 = h2(pkh(__builtin_amdgcn_exp2f(acc0[0]), __builtin_amdgcn_exp2f(acc0[1])));
            const half2v e23 = h2(pkh(__builtin_amdgcn_exp2f(acc0[2]), __builtin_amdgcn_exp2f(acc0[3])));
            const half2v f01 = h2(pkh(__builtin_amdgcn_exp2f(acc1[0]), __builtin_amdgcn_exp2f(acc1[1])));
            const half2v f23 = h2(pkh(__builtin_amdgcn_exp2f(acc1[2]), __builtin_amdgcn_exp2f(acc1[3])));
            ssum2[gg * 4 + 0] += e01;
            ssum2[gg * 4 + 1] += e23;
            ssum2[gg * 4 + 2] += f01;
            ssum2[gg * 4 + 3] += f23;
            wv2[gg * 4 + 0] = __builtin_elementwise_fma(e01, h2(vA.x), wv2[gg * 4 + 0]);
            wv2[gg * 4 + 1] = __builtin_elementwise_fma(e23, h2(vA.y), wv2[gg * 4 + 1]);
            wv2[gg * 4 + 2] = __builtin_elementwise_fma(f01, h2(vB.x), wv2[gg * 4 + 2]);
            wv2[gg * 4 + 3] = __builtin_elementwise_fma(f23, h2(vB.y), wv2[gg * 4 + 3]);
        }

        // ---- rotate prefetched state ----
#pragma unroll
        for (int j = 0; j < 8; ++j) kc[j] = kn[j];
        Sk = SkN;
        nofs = nofsN;
        relOff += step;
        m3 = (m3 == 2) ? 0 : m3 + 1;
    }

    // ---- merge group 1 partials into group 0 (packed, 32 words/thread) ----
    __syncthreads();
    if (grp == 1) {
#pragma unroll
        for (int j4 = 0; j4 < 4; ++j4) {
            uint4 o;
            o.x = u2(wv2[j4 * 4 + 0]); o.y = u2(wv2[j4 * 4 + 1]);
            o.z = u2(wv2[j4 * 4 + 2]); o.w = u2(wv2[j4 * 4 + 3]);
            *(uint4*)(hidL + j4 * 4096 + p * 16) = o;
        }
#pragma unroll
        for (int j4 = 0; j4 < 4; ++j4) {
            uint4 o;
            o.x = u2(ssum2[j4 * 4 + 0]); o.y = u2(ssum2[j4 * 4 + 1]);
            o.z = u2(ssum2[j4 * 4 + 2]); o.w = u2(ssum2[j4 * 4 + 3]);
            *(uint4*)(hidL + (4 + j4) * 4096 + p * 16) = o;
        }
    }
    __syncthreads();
    if (grp == 0) {
#pragma unroll
        for (int j4 = 0; j4 < 4; ++j4) {
            const uint4 t = *(const uint4*)(hidL + j4 * 4096 + p * 16);
            wv2[j4 * 4 + 0] += h2(t.x); wv2[j4 * 4 + 1] += h2(t.y);
            wv2[j4 * 4 + 2] += h2(t.z); wv2[j4 * 4 + 3] += h2(t.w);
        }
#pragma unroll
        for (int j4 = 0; j4 < 4; ++j4) {
            const uint4 t = *(const uint4*)(hidL + (4 + j4) * 4096 + p * 16);
            ssum2[j4 * 4 + 0] += h2(t.x); ssum2[j4 * 4 + 1] += h2(t.y);
            ssum2[j4 * 4 + 2] += h2(t.z); ssum2[j4 * 4 + 3] += h2(t.w);
        }
#pragma unroll
        for (int gg = 0; gg < 4; ++gg) {
            const int g = wrow * 4 + gg;
            float* op = out + (size_t)b * (32 * HWm) + ((h0 + g) << 8) + (w0 + lane15);
#pragma unroll
            for (int r = 0; r < 4; ++r) {
                const int ch0 = q * 4 + r;
                const int ch1 = 16 + q * 4 + r;
                const float w0v = (float)((r < 2) ? wv2[gg * 4 + 0][r] : wv2[gg * 4 + 1][r - 2]);
                const float s0v = (float)((r < 2) ? ssum2[gg * 4 + 0][r] : ssum2[gg * 4 + 1][r - 2]);
                const float w1v = (float)((r < 2) ? wv2[gg * 4 + 2][r] : wv2[gg * 4 + 3][r - 2]);
                const float s1v = (float)((r < 2) ? ssum2[gg * 4 + 2][r] : ssum2[gg * 4 + 3][r - 2]);
                op[ch0 * HWm] += w0v * __builtin_amdgcn_rcpf(s0v);
                op[ch1 * HWm] += w1v * __builtin_amdgcn_rcpf(s1v);
            }
        }
    }
}

extern "C" void kernel_launch(void* const* d_in, const int* in_sizes, int n_in,
                              void* d_out, int out_size, void* d_ws, size_t ws_size,
                              hipStream_t stream) {
    const float* x    = (const float*)d_in[0];
    const float* Wqkv = (const float*)d_in[1];
    const float* W1   = (const float*)d_in[2];
    const float* b1   = (const float*)d_in[3];
    const float* lnw  = (const float*)d_in[4];
    const float* lnb  = (const float*)d_in[5];
    const float* W2   = (const float*)d_in[6];
    const float* b2   = (const float*)d_in[7];
    const float* Wg   = (const float*)d_in[8];
    const float* bg   = (const float*)d_in[9];
    float* out = (float*)d_out;

    float* ws  = (float*)d_ws;
    float* Wk1 = ws;                                  // 2048 f32
    float* Wq1 = ws + 2048;                           // 2048 f32
    unsigned* W2A  = (unsigned*)(ws + 4096);          // 1024 u32
    unsigned* waA  = (unsigned*)(ws + 5120);          // 3072 u32
    float*    biasF = ws + 8192;                      // 3072 f32
    unsigned* beta2G = (unsigned*)(ws + 11264);       // 32 u32
    float*    b2adj  = ws + 11296;                    // 32 f32
    unsigned* khP = (unsigned*)(ws + 11328);          // 4*PHW*32 u32 (padded)
    unsigned* qhg = khP + (size_t)4 * PHW * 32;       // NPIX*32 u32
    unsigned* vP  = qhg + (size_t)NPIX * 32;          // 4*PHW*16 u32 (padded)
    float* SkP = (float*)(vP + (size_t)4 * PHW * 16); // 4*PHW f32 (padded)
    float* SqG = SkP + (size_t)4 * PHW;               // NPIX f32

    prep_kernel<<<1, 256, 0, stream>>>(Wqkv, W1, W2, b1, Wg, bg, lnw, lnb, b2,
                                       Wk1, Wq1, W2A, waA, biasF, beta2G, b2adj);
    kv_kernel<<<1024 + 17, 256, 0, stream>>>(x, (const half8*)waA,
                                             (const float4*)biasF,
                                             khP, qhg, vP, SkP, SqG, out);
    attn_kernel<<<1024, 512, 0, stream>>>(qhg, khP, vP, (const half8*)W2A,
                                          SkP, SqG, beta2G, b2adj, out);
}

// Round 16
// 121.311 us; speedup vs baseline: 1.4196x; 1.4196x over previous
//
#include <hip/hip_runtime.h>

// VectorAttention: B=4, C=32, H=256, W=256, HID=64, all fp32 in/out.
// hid_n = (Wq1@x + b1) - (Wk1@x)|neighbor ; scores = W2@relu(LN(hid)) via MFMA.
// fp16 intermediates. kh/v/Sk zero-padded (258x258).
// attn: fragment-parallel — each lane computes ONLY its MFMA B-fragment channels
// (chunks q,4+q of 4 pixels); LN stats via 4-lane shfl_xor reduce. No hid LDS.
// b2 dropped (softmax over neighbors is invariant to per-channel constants).

#define HWm 65536
#define NPIX 262144
#define PW 258
#define PHW 66564   // 258*258
#define LOG2E 1.44269504088896340736f

typedef __attribute__((ext_vector_type(8))) _Float16 half8;
typedef __attribute__((ext_vector_type(2))) _Float16 half2v;
typedef __attribute__((ext_vector_type(4))) float f32x4;

__device__ __forceinline__ unsigned pkh(float a, float b) {
    auto h = __builtin_amdgcn_cvt_pkrtz(a, b);   // __fp16 ext_vector(2)
    return __builtin_bit_cast(unsigned, h);
}
__device__ __forceinline__ half2v h2(unsigned u) { return __builtin_bit_cast(half2v, u); }
__device__ __forceinline__ unsigned u2(half2v h) { return __builtin_bit_cast(unsigned, h); }

// ---------------- kernel 0: weight prep ----------------
// Wall rows: 0-63 Wk1 | 64-127 Wq1 | 128-159 Wqkv[64:96] (v) | 160-191 Wg+I
__global__ __launch_bounds__(256) void prep_kernel(
    const float* __restrict__ Wqkv, const float* __restrict__ W1,
    const float* __restrict__ W2, const float* __restrict__ b1v,
    const float* __restrict__ Wg, const float* __restrict__ bgv,
    const float* __restrict__ lnw, const float* __restrict__ lnb,
    float* __restrict__ Wk1, float* __restrict__ Wq1,
    unsigned* __restrict__ W2A, unsigned* __restrict__ waA,
    float* __restrict__ biasF, unsigned* __restrict__ beta2G)
{
    const int tid = threadIdx.x;
    for (int i = tid; i < 2048; i += 256) {
        const int d = i >> 5, c = i & 31;
        float aq = 0.f, ak = 0.f;
#pragma unroll
        for (int k = 0; k < 32; ++k) {
            const float w1 = W1[d * 32 + k];
            aq = fmaf(w1, Wqkv[k * 32 + c], aq);
            ak = fmaf(w1, Wqkv[(32 + k) * 32 + c], ak);
        }
        Wq1[i] = aq;
        Wk1[i] = ak;
    }
    // W2 A-fragments: fold lnw (assumed >0; ~0 -> dead channel) and log2e.
    for (int i = tid; i < 1024; i += 256) {
        const int w = i & 3;
        const int lane = (i >> 2) & 63;
        const int kb = (i >> 8) & 1;
        const int ct = (i >> 9) & 1;
        const int row = (lane & 15) + 16 * ct;
        const int k0 = kb * 32 + ((lane >> 4) & 3) * 8 + 2 * w;
        const float s0 = (fabsf(lnw[k0]) < 1e-8f) ? 0.f : lnw[k0] * LOG2E;
        const float s1 = (fabsf(lnw[k0 + 1]) < 1e-8f) ? 0.f : lnw[k0 + 1] * LOG2E;
        W2A[i] = pkh(W2[row * 64 + k0] * s0, W2[row * 64 + k0 + 1] * s1);
    }
    // beta pairs (lnb/lnw; lnw~0 handled as 0 — its constant contribution
    // cancels in the softmax over neighbors)
    for (int i = tid; i < 32; i += 256) {
        const float w0 = lnw[2 * i], w1 = lnw[2 * i + 1];
        const float be0 = (fabsf(w0) < 1e-8f) ? 0.f : lnb[2 * i] / w0;
        const float be1 = (fabsf(w1) < 1e-8f) ? 0.f : lnb[2 * i + 1] / w1;
        beta2G[i] = pkh(be0, be1);
    }
    __syncthreads();
    // Wall A-fragments (fp16)
    for (int i = tid; i < 3072; i += 256) {
        const int t = i >> 8;
        const int l = (i >> 2) & 63;
        const int w2 = i & 3;
        const int row = 16 * t + (l & 15);
        const int k0 = ((l >> 4) & 3) * 8 + 2 * w2;
        float a0, a1;
        if (row < 64)        { a0 = Wk1[row * 32 + k0];            a1 = Wk1[row * 32 + k0 + 1]; }
        else if (row < 128)  { a0 = Wq1[(row - 64) * 32 + k0];     a1 = Wq1[(row - 64) * 32 + k0 + 1]; }
        else if (row < 160)  { a0 = Wqkv[(row - 64) * 32 + k0];    a1 = Wqkv[(row - 64) * 32 + k0 + 1]; }
        else {
            const int gr = row - 160;
            a0 = Wg[gr * 32 + k0]     + ((gr == k0)     ? 1.f : 0.f);
            a1 = Wg[gr * 32 + k0 + 1] + ((gr == k0 + 1) ? 1.f : 0.f);
        }
        waA[i] = pkh(a0, a1);
    }
    // bias fragments (kv GEMM C-init)
    for (int i = tid; i < 3072; i += 256) {
        const int t = i >> 8;
        const int l = (i >> 2) & 63;
        const int r = i & 3;
        const int row = 16 * t + ((l >> 4) & 3) * 4 + r;
        float bv = 0.f;
        if (row >= 64 && row < 128) bv = b1v[row - 64];
        else if (row >= 160)        bv = bgv[row - 160];
        biasF[i] = bv;
    }
}

// ---------------- kernel 1: MFMA projections (fp16) ----------------
__global__ __launch_bounds__(256) void kv_kernel(
    const float* __restrict__ x, const half8* __restrict__ waA,
    const float4* __restrict__ biasF, unsigned* __restrict__ khP,
    unsigned* __restrict__ qhg, unsigned* __restrict__ vP,
    float* __restrict__ SkP, float* __restrict__ SqG,
    float* __restrict__ out)
{
    const int bid = blockIdx.x;
    const int tid = threadIdx.x;

    if (bid >= 1024) {
        const int t = (bid - 1024) * 256 + tid;
        if (t < 4112) {
            const int bb = t / 1028;
            const int rr = t - bb * 1028;
            int hh, ww;
            if (rr < 258)      { hh = 0;             ww = rr; }
            else if (rr < 516) { hh = 257;           ww = rr - 258; }
            else if (rr < 772) { hh = rr - 516 + 1;  ww = 0; }
            else               { hh = rr - 772 + 1;  ww = 257; }
            const size_t pixP = (size_t)bb * PHW + hh * PW + ww;
            uint4* kp = (uint4*)khP + pixP * 8;
            uint4* vp = (uint4*)vP + pixP * 4;
            const uint4 z = { 0u, 0u, 0u, 0u };
#pragma unroll
            for (int i = 0; i < 8; ++i) kp[i] = z;
#pragma unroll
            for (int i = 0; i < 4; ++i) vp[i] = z;
            SkP[pixP] = 0.f;
        }
        return;
    }

    __shared__ __align__(16) unsigned xT[256 * 16];   // 16 KB

    const int b = bid >> 8;
    const int h = bid & 255;
    const int pix0 = bid * 256;
    const int rowP0 = b * PHW + (h + 1) * PW + 1;

    {
        const float* xp = x + (size_t)b * (32 * HWm) + h * 256 + tid;
        float xv[32];
#pragma unroll
        for (int c = 0; c < 32; ++c) xv[c] = xp[c * HWm];
        unsigned* myx = &xT[tid * 16];
#pragma unroll
        for (int cc = 0; cc < 4; ++cc) {
            uint4 u;
            u.x = pkh(xv[cc * 8 + 0], xv[cc * 8 + 1]);
            u.y = pkh(xv[cc * 8 + 2], xv[cc * 8 + 3]);
            u.z = pkh(xv[cc * 8 + 4], xv[cc * 8 + 5]);
            u.w = pkh(xv[cc * 8 + 6], xv[cc * 8 + 7]);
            *(uint4*)(myx + (((cc + tid) & 3) * 4)) = u;
        }
    }
    // no barrier: wave-local staging + reads

    const int l = tid & 63;
    const int wid = tid >> 6;
    const int g = l >> 4;
    const int c15 = l & 15;

    half8 A[12];
    f32x4 bF[12];
#pragma unroll
    for (int t = 0; t < 12; ++t) {
        A[t] = waA[t * 64 + l];
        const float4 bv = biasF[t * 64 + l];
        bF[t][0] = bv.x; bF[t][1] = bv.y; bF[t][2] = bv.z; bF[t][3] = bv.w;
    }

#pragma unroll
    for (int pp = 0; pp < 4; ++pp) {
        const int pg = wid * 4 + pp;
        const int px = pg * 16 + c15;
        const half8 bfrag = *(const half8*)&xT[px * 16 + (((g + px) & 3) * 4)];

        f32x4 Ct[12];
#pragma unroll
        for (int t = 0; t < 12; ++t)
            Ct[t] = __builtin_amdgcn_mfma_f32_16x16x32_f16(A[t], bfrag, bF[t], 0, 0, 0);

        const size_t pixP = (size_t)(rowP0 + px);
        const int pixg = pix0 + px;

        float sk = 0.f;
        {
            char* krec = (char*)khP + pixP * 128 + g * 8;
#pragma unroll
            for (int t = 0; t < 4; ++t) {
                uint2 uu;
                uu.x = pkh(Ct[t][0], Ct[t][1]);
                uu.y = pkh(Ct[t][2], Ct[t][3]);
                *(uint2*)(krec + t * 32) = uu;
                sk += (Ct[t][0] + Ct[t][1]) + (Ct[t][2] + Ct[t][3]);
            }
        }
        float sq = 0.f;
        {
            char* qrec = (char*)qhg + (size_t)pixg * 128 + g * 8;
#pragma unroll
            for (int t = 4; t < 8; ++t) {
                uint2 uu;
                uu.x = pkh(Ct[t][0], Ct[t][1]);
                uu.y = pkh(Ct[t][2], Ct[t][3]);
                *(uint2*)(qrec + (t - 4) * 32) = uu;
                sq += (Ct[t][0] + Ct[t][1]) + (Ct[t][2] + Ct[t][3]);
            }
        }
        {
            char* vrec = (char*)vP + pixP * 64 + g * 8;
#pragma unroll
            for (int t = 8; t < 10; ++t) {
                uint2 uu;
                uu.x = pkh(Ct[t][0], Ct[t][1]);
                uu.y = pkh(Ct[t][2], Ct[t][3]);
                *(uint2*)(vrec + (t - 8) * 32) = uu;
            }
        }
        {
            float* op = out + (size_t)b * (32 * HWm) + h * 256 + px;
#pragma unroll
            for (int t = 10; t < 12; ++t) {
#pragma unroll
                for (int r = 0; r < 4; ++r)
                    op[(16 * (t - 10) + g * 4 + r) * HWm] = Ct[t][r];
            }
        }
        sk += __shfl_xor(sk, 16);
        sk += __shfl_xor(sk, 32);
        sq += __shfl_xor(sq, 16);
        sq += __shfl_xor(sq, 32);
        if (g == 0) {
            SkP[pixP] = sk;
            SqG[pixg] = sq;
        }
    }
}

// ---------------- kernel 2: fragment-parallel MFMA attention ----------------
// 512 threads, 2 neighbor-groups. Lane computes chunks {q,4+q} of its 4 MFMA
// pixels directly; LN stats via shfl_xor(16/32); no hid LDS; merge via LDS.
__global__ __launch_bounds__(512) void attn_kernel(
    const unsigned* __restrict__ qhg, const unsigned* __restrict__ khP,
    const unsigned* __restrict__ vP, const half8* __restrict__ w2a,
    const float* __restrict__ SkP, const float* __restrict__ SqG,
    const unsigned* __restrict__ beta2G, float* __restrict__ out)
{
    __shared__ __align__(16) char mergeL[32768];

    const int tid = threadIdx.x;
    const int grp = tid >> 8;
    const int p = tid & 255;

    const int bid = blockIdx.x;
    const int swz = (bid & 7) * 128 + (bid >> 3);
    const int b = swz >> 8;
    const int trem = swz & 255;
    const int h0 = (trem >> 4) << 4;
    const int w0 = (trem & 15) << 4;

    const int l = tid & 63;
    const int lane15 = p & 15;
    const int q = (p >> 4) & 3;
    const int wrow = (p >> 6) & 3;
    const int gRow0 = wrow * 4;

    // the 4 pixels this lane serves in the MFMA (rows gRow0..+3, col lane15)
    const int pixU0 = (b << 16) + ((h0 + gRow0) << 8) + (w0 + lane15);   // +gg*256
    const int pixP0 = b * PHW + (h0 + gRow0 + 1) * PW + (w0 + lane15 + 1); // +gg*PW

    // qh fragments (chunks q, 4+q) + Sq for the 4 pixels
    uint4 qf[4][2];
    float Sq4[4];
#pragma unroll
    for (int gg = 0; gg < 4; ++gg) {
        const uint4* qr = (const uint4*)qhg + (size_t)(pixU0 + gg * 256) * 8;
        qf[gg][0] = qr[q];
        qf[gg][1] = qr[4 + q];
        Sq4[gg] = SqG[pixU0 + gg * 256];
    }

    // beta for this lane's chunks
    half2v bet[2][4];
#pragma unroll
    for (int j = 0; j < 4; ++j) {
        bet[0][j] = h2(beta2G[q * 4 + j]);
        bet[1][j] = h2(beta2G[(4 + q) * 4 + j]);
    }

    const half8 a00 = w2a[0 * 64 + l];
    const half8 a01 = w2a[1 * 64 + l];
    const half8 a10 = w2a[2 * 64 + l];
    const half8 a11 = w2a[3 * 64 + l];

    half2v wv2[16], ssum2[16];
    const half2v zero2 = { (_Float16)0.f, (_Float16)0.f };
#pragma unroll
    for (int i = 0; i < 16; ++i) { wv2[i] = zero2; ssum2[i] = zero2; }

    const uint4* khP4 = (const uint4*)khP;
    const int vbase0 = b * PHW + (h0 + 1) * PW + (w0 + 1) + lane15;  // + g*PW + relOff

    const int cnt = grp ? 5 : 4;
    int relOff = grp ? 0 : (-PW - 1);
    int m3 = grp ? 1 : 0;

#pragma unroll
    for (int nn = 0; nn < 5; ++nn) {
        if (nn >= cnt) break;

        // ---- per-gg independent chains: load kh fragments + Sk, stats ----
        float ss[4];
        half2v hd[4][2][4];
#pragma unroll
        for (int gg = 0; gg < 4; ++gg) {
            const int nofs = pixP0 + gg * PW + relOff;
            const uint4* kr = khP4 + (size_t)nofs * 8;
            const uint4 k0 = kr[q];
            const uint4 k1 = kr[4 + q];
            hd[gg][0][0] = h2(qf[gg][0].x) - h2(k0.x);
            hd[gg][0][1] = h2(qf[gg][0].y) - h2(k0.y);
            hd[gg][0][2] = h2(qf[gg][0].z) - h2(k0.z);
            hd[gg][0][3] = h2(qf[gg][0].w) - h2(k0.w);
            hd[gg][1][0] = h2(qf[gg][1].x) - h2(k1.x);
            hd[gg][1][1] = h2(qf[gg][1].y) - h2(k1.y);
            hd[gg][1][2] = h2(qf[gg][1].z) - h2(k1.z);
            hd[gg][1][3] = h2(qf[gg][1].w) - h2(k1.w);
            float s = 0.f;
#pragma unroll
            for (int c = 0; c < 2; ++c)
#pragma unroll
                for (int j = 0; j < 4; ++j)
                    s = __builtin_amdgcn_fdot2(hd[gg][c][j], hd[gg][c][j], s, false);
            ss[gg] = s;
        }
        // 4-lane reduce (lanes l, l^16, l^32, l^48 share a pixel)
#pragma unroll
        for (int gg = 0; gg < 4; ++gg) {
            ss[gg] += __shfl_xor(ss[gg], 16);
            ss[gg] += __shfl_xor(ss[gg], 32);
        }

        // ---- per-gg: normalize fragments in-reg, MFMA, softmax accumulate ----
#pragma unroll
        for (int gg = 0; gg < 4; ++gg) {
            const float Sk = SkP[pixP0 + gg * PW + relOff];
            const float sum = Sq4[gg] - Sk;
            const float mean = sum * 0.015625f;
            float var = fmaf(-mean, mean, ss[gg] * 0.015625f);
            var = fmaxf(var, 0.f);
            const float inv = __builtin_amdgcn_rcpf(sqrtf(var) + 1e-5f);
            const float nmi = -mean * inv;
            const half2v inv2 = { (_Float16)inv, (_Float16)inv };
            const half2v nmi2 = { (_Float16)nmi, (_Float16)nmi };

            uint4 u0, u1;
            {
                unsigned uw[2][4];
#pragma unroll
                for (int c = 0; c < 2; ++c)
#pragma unroll
                    for (int j = 0; j < 4; ++j) {
                        half2v u = __builtin_elementwise_fma(hd[gg][c][j], inv2, nmi2 + bet[c][j]);
                        u = __builtin_elementwise_max(u, zero2);
                        uw[c][j] = u2(u);
                    }
                u0.x = uw[0][0]; u0.y = uw[0][1]; u0.z = uw[0][2]; u0.w = uw[0][3];
                u1.x = uw[1][0]; u1.y = uw[1][1]; u1.z = uw[1][2]; u1.w = uw[1][3];
            }
            const half8 B0 = __builtin_bit_cast(half8, u0);
            const half8 B1 = __builtin_bit_cast(half8, u1);

            const f32x4 z4 = { 0.f, 0.f, 0.f, 0.f };
            f32x4 acc0 = __builtin_amdgcn_mfma_f32_16x16x32_f16(a00, B0, z4, 0, 0, 0);
            acc0 = __builtin_amdgcn_mfma_f32_16x16x32_f16(a01, B1, acc0, 0, 0, 0);
            f32x4 acc1 = __builtin_amdgcn_mfma_f32_16x16x32_f16(a10, B0, z4, 0, 0, 0);
            acc1 = __builtin_amdgcn_mfma_f32_16x16x32_f16(a11, B1, acc1, 0, 0, 0);

            const int npP = vbase0 + (gRow0 + gg) * PW + relOff;
            const unsigned* vp = vP + (size_t)npP * 16;
            const uint2 vA = *(const uint2*)(vp + q * 2);
            const uint2 vB = *(const uint2*)(vp + 8 + q * 2);

            const half2v e01 = h2(pkh(__builtin_amdgcn_exp2f(acc0[0]), __builtin_amdgcn_exp2f(acc0[1])));
            const half2v e23 = h2(pkh(__builtin_amdgcn_exp2f(acc0[2]), __builtin_amdgcn_exp2f(acc0[3])));
            const half2v f01 = h2(pkh(__builtin_amdgcn_exp2f(acc1[0]), __builtin_amdgcn_exp2f(acc1[1])));
            const half2v f23 = h2(pkh(__builtin_amdgcn_exp2f(acc1[2]), __builtin_amdgcn_exp2f(acc1[3])));
            ssum2[gg * 4 + 0] += e01;
            ssum2[gg * 4 + 1] += e23;
            ssum2[gg * 4 + 2] += f01;
            ssum2[gg * 4 + 3] += f23;
            wv2[gg * 4 + 0] = __builtin_elementwise_fma(e01, h2(vA.x), wv2[gg * 4 + 0]);
            wv2[gg * 4 + 1] = __builtin_elementwise_fma(e23, h2(vA.y), wv2[gg * 4 + 1]);
            wv2[gg * 4 + 2] = __builtin_elementwise_fma(f01, h2(vB.x), wv2[gg * 4 + 2]);
            wv2[gg * 4 + 3] = __builtin_elementwise_fma(f23, h2(vB.y), wv2[gg * 4 + 3]);
        }

        const int step = (m3 == 2) ? (PW - 2) : 1;
        relOff += step;
        m3 = (m3 == 2) ? 0 : m3 + 1;
    }

    // ---- merge group 1 partials into group 0 (packed) ----
    __syncthreads();
    if (grp == 1) {
#pragma unroll
        for (int j4 = 0; j4 < 4; ++j4) {
            uint4 o;
            o.x = u2(wv2[j4 * 4 + 0]); o.y = u2(wv2[j4 * 4 + 1]);
            o.z = u2(wv2[j4 * 4 + 2]); o.w = u2(wv2[j4 * 4 + 3]);
            *(uint4*)(mergeL + j4 * 4096 + p * 16) = o;
        }
#pragma unroll
        for (int j4 = 0; j4 < 4; ++j4) {
            uint4 o;
            o.x = u2(ssum2[j4 * 4 + 0]); o.y = u2(ssum2[j4 * 4 + 1]);
            o.z = u2(ssum2[j4 * 4 + 2]); o.w = u2(ssum2[j4 * 4 + 3]);
            *(uint4*)(mergeL + (4 + j4) * 4096 + p * 16) = o;
        }
    }
    __syncthreads();
    if (grp == 0) {
#pragma unroll
        for (int j4 = 0; j4 < 4; ++j4) {
            const uint4 t = *(const uint4*)(mergeL + j4 * 4096 + p * 16);
            wv2[j4 * 4 + 0] += h2(t.x); wv2[j4 * 4 + 1] += h2(t.y);
            wv2[j4 * 4 + 2] += h2(t.z); wv2[j4 * 4 + 3] += h2(t.w);
        }
#pragma unroll
        for (int j4 = 0; j4 < 4; ++j4) {
            const uint4 t = *(const uint4*)(mergeL + (4 + j4) * 4096 + p * 16);
            ssum2[j4 * 4 + 0] += h2(t.x); ssum2[j4 * 4 + 1] += h2(t.y);
            ssum2[j4 * 4 + 2] += h2(t.z); ssum2[j4 * 4 + 3] += h2(t.w);
        }
#pragma unroll
        for (int gg = 0; gg < 4; ++gg) {
            const int g = gRow0 + gg;
            float* op = out + (size_t)b * (32 * HWm) + ((h0 + g) << 8) + (w0 + lane15);
#pragma unroll
            for (int r = 0; r < 4; ++r) {
                const int ch0 = q * 4 + r;
                const int ch1 = 16 + q * 4 + r;
                const float w0v = (float)((r < 2) ? wv2[gg * 4 + 0][r] : wv2[gg * 4 + 1][r - 2]);
                const float s0v = (float)((r < 2) ? ssum2[gg * 4 + 0][r] : ssum2[gg * 4 + 1][r - 2]);
                const float w1v = (float)((r < 2) ? wv2[gg * 4 + 2][r] : wv2[gg * 4 + 3][r - 2]);
                const float s1v = (float)((r < 2) ? ssum2[gg * 4 + 2][r] : ssum2[gg * 4 + 3][r - 2]);
                op[ch0 * HWm] += w0v * __builtin_amdgcn_rcpf(s0v);
                op[ch1 * HWm] += w1v * __builtin_amdgcn_rcpf(s1v);
            }
        }
    }
}

extern "C" void kernel_launch(void* const* d_in, const int* in_sizes, int n_in,
                              void* d_out, int out_size, void* d_ws, size_t ws_size,
                              hipStream_t stream) {
    const float* x    = (const float*)d_in[0];
    const float* Wqkv = (const float*)d_in[1];
    const float* W1   = (const float*)d_in[2];
    const float* b1   = (const float*)d_in[3];
    const float* lnw  = (const float*)d_in[4];
    const float* lnb  = (const float*)d_in[5];
    const float* W2   = (const float*)d_in[6];
    const float* b2   = (const float*)d_in[7];
    const float* Wg   = (const float*)d_in[8];
    const float* bg   = (const float*)d_in[9];
    float* out = (float*)d_out;
    (void)b2;  // cancels in softmax over neighbors

    float* ws  = (float*)d_ws;
    float* Wk1 = ws;                                  // 2048 f32
    float* Wq1 = ws + 2048;                           // 2048 f32
    unsigned* W2A  = (unsigned*)(ws + 4096);          // 1024 u32
    unsigned* waA  = (unsigned*)(ws + 5120);          // 3072 u32
    float*    biasF = ws + 8192;                      // 3072 f32
    unsigned* beta2G = (unsigned*)(ws + 11264);       // 32 u32
    unsigned* khP = (unsigned*)(ws + 11328);          // 4*PHW*32 u32 (padded)
    unsigned* qhg = khP + (size_t)4 * PHW * 32;       // NPIX*32 u32
    unsigned* vP  = qhg + (size_t)NPIX * 32;          // 4*PHW*16 u32 (padded)
    float* SkP = (float*)(vP + (size_t)4 * PHW * 16); // 4*PHW f32 (padded)
    float* SqG = SkP + (size_t)4 * PHW;               // NPIX f32

    prep_kernel<<<1, 256, 0, stream>>>(Wqkv, W1, W2, b1, Wg, bg, lnw, lnb,
                                       Wk1, Wq1, W2A, waA, biasF, beta2G);
    kv_kernel<<<1024 + 17, 256, 0, stream>>>(x, (const half8*)waA,
                                             (const float4*)biasF,
                                             khP, qhg, vP, SkP, SqG, out);
    attn_kernel<<<1024, 512, 0, stream>>>(qhg, khP, vP, (const half8*)W2A,
                                          SkP, SqG, beta2G, out);
}